// Round 1
// baseline (286.775 us; speedup 1.0000x reference)
//
#include <hip/hip_runtime.h>
#include <math.h>

#define EPSV 1e-5f
#define NB_STATS 1024

// ---------------------------------------------------------------------------
// Pass 1: per-channel sum/sumsq of relu(conv1(x)+b1)  (16 channels, over B*3)
// partials layout: partials[block*32 + v], v<16 = sum[ch v], v>=16 = sq[ch v-16]
// ---------------------------------------------------------------------------
__global__ __launch_bounds__(256) void k_stats1(const float* __restrict__ x,
                                                const float* __restrict__ w1,
                                                const float* __restrict__ b1,
                                                float* __restrict__ partials,
                                                int B)
{
    float sum[16], sq[16];
#pragma unroll
    for (int i = 0; i < 16; ++i) { sum[i] = 0.f; sq[i] = 0.f; }

    int tid = blockIdx.x * 256 + threadIdx.x;
    int stride = gridDim.x * 256;
    for (int s = tid; s < B; s += stride) {
        float x0 = x[3*s], x1 = x[3*s+1], x2 = x[3*s+2];
#pragma unroll
        for (int o = 0; o < 16; ++o) {
            float wa = w1[3*o], wb = w1[3*o+1], wc = w1[3*o+2], bb = b1[o];
            float t0 = fmaxf(fmaf(wb, x0, fmaf(wc, x1, bb)), 0.f);
            float t1 = fmaxf(fmaf(wa, x0, fmaf(wb, x1, fmaf(wc, x2, bb))), 0.f);
            float t2 = fmaxf(fmaf(wa, x1, fmaf(wb, x2, bb)), 0.f);
            sum[o] += t0 + t1 + t2;
            sq[o]  = fmaf(t0, t0, fmaf(t1, t1, fmaf(t2, t2, sq[o])));
        }
    }

    __shared__ float red[4][32];
    int lane = threadIdx.x & 63, wid = threadIdx.x >> 6;
#pragma unroll
    for (int v = 0; v < 16; ++v) {
        float a = sum[v], b = sq[v];
#pragma unroll
        for (int off = 32; off >= 1; off >>= 1) {
            a += __shfl_down(a, off, 64);
            b += __shfl_down(b, off, 64);
        }
        if (lane == 0) { red[wid][v] = a; red[wid][16 + v] = b; }
    }
    __syncthreads();
    if (threadIdx.x < 32) {
        float r = red[0][threadIdx.x] + red[1][threadIdx.x] +
                  red[2][threadIdx.x] + red[3][threadIdx.x];
        partials[blockIdx.x * 32 + threadIdx.x] = r;
    }
}

// ---------------------------------------------------------------------------
// Finalize 1: reduce partials -> BN1 scale/shift, fold into conv2 weights.
// w2f[3*o+k] = w2[3*o+k] * scale1[o/2]
// b2f[3*o+p] = b2[o] + shift1[o/2] * (sum of w2 taps valid at position p)
// ---------------------------------------------------------------------------
__global__ __launch_bounds__(256) void k_fin1(const float* __restrict__ partials,
                                              const float* __restrict__ g1,
                                              const float* __restrict__ bt1,
                                              const float* __restrict__ w2,
                                              const float* __restrict__ b2,
                                              float* __restrict__ w2f,
                                              float* __restrict__ b2f,
                                              float Ninv, int nb)
{
    __shared__ float red[8][32];
    __shared__ float tot[32];
    __shared__ float ssc[16], ssh[16];
    int t = threadIdx.x;
    {
        int v = t & 31, c = t >> 5;
        float a = 0.f;
        for (int b = c; b < nb; b += 8) a += partials[b * 32 + v];
        red[c][v] = a;
    }
    __syncthreads();
    if (t < 32) {
        float a = 0.f;
#pragma unroll
        for (int c = 0; c < 8; ++c) a += red[c][t];
        tot[t] = a;
    }
    __syncthreads();
    if (t < 16) {
        float mean = tot[t] * Ninv;
        float var  = fmaxf(tot[16 + t] * Ninv - mean * mean, 0.f);
        float rstd = rsqrtf(var + EPSV);
        float sc = g1[t] * rstd;
        ssc[t] = sc;
        ssh[t] = bt1[t] - mean * sc;
    }
    __syncthreads();
    if (t < 96) {
        int o = t / 3, p = t % 3;
        int g = o >> 1;
        w2f[t] = w2[t] * ssc[g];
        float wv0 = w2[3*o], wv1 = w2[3*o+1], wv2 = w2[3*o+2];
        float sv = (p == 0) ? (wv1 + wv2) : ((p == 1) ? (wv0 + wv1 + wv2) : (wv0 + wv1));
        b2f[t] = b2[o] + ssh[g] * sv;
    }
}

// ---------------------------------------------------------------------------
// Pass 2: per-channel sum/sumsq of relu(conv2(bn1(relu1)))  (32 channels)
// Uses folded w2f/b2f so BN1 costs nothing.
// partials layout: partials[block*64 + v], v<32 = sum, v>=32 = sq
// ---------------------------------------------------------------------------
__global__ __launch_bounds__(256) void k_stats2(const float* __restrict__ x,
                                                const float* __restrict__ w1,
                                                const float* __restrict__ b1,
                                                const float* __restrict__ w2f,
                                                const float* __restrict__ b2f,
                                                float* __restrict__ partials,
                                                int B)
{
    float sum[32], sq[32];
#pragma unroll
    for (int i = 0; i < 32; ++i) { sum[i] = 0.f; sq[i] = 0.f; }

    int tid = blockIdx.x * 256 + threadIdx.x;
    int stride = gridDim.x * 256;
    for (int s = tid; s < B; s += stride) {
        float x0 = x[3*s], x1 = x[3*s+1], x2 = x[3*s+2];
#pragma unroll
        for (int g = 0; g < 16; ++g) {
            float wa = w1[3*g], wb = w1[3*g+1], wc = w1[3*g+2], bb = b1[g];
            float r0 = fmaxf(fmaf(wb, x0, fmaf(wc, x1, bb)), 0.f);
            float r1 = fmaxf(fmaf(wa, x0, fmaf(wb, x1, fmaf(wc, x2, bb))), 0.f);
            float r2 = fmaxf(fmaf(wa, x1, fmaf(wb, x2, bb)), 0.f);
#pragma unroll
            for (int j = 0; j < 2; ++j) {
                int o = 2 * g + j;
                float ua = w2f[3*o], ub = w2f[3*o+1], uc = w2f[3*o+2];
                float v0 = fmaxf(fmaf(ub, r0, fmaf(uc, r1, b2f[3*o+0])), 0.f);
                float v1 = fmaxf(fmaf(ua, r0, fmaf(ub, r1, fmaf(uc, r2, b2f[3*o+1]))), 0.f);
                float v2 = fmaxf(fmaf(ua, r1, fmaf(ub, r2, b2f[3*o+2])), 0.f);
                sum[o] += v0 + v1 + v2;
                sq[o]  = fmaf(v0, v0, fmaf(v1, v1, fmaf(v2, v2, sq[o])));
            }
        }
    }

    __shared__ float red[4][64];
    int lane = threadIdx.x & 63, wid = threadIdx.x >> 6;
#pragma unroll
    for (int v = 0; v < 32; ++v) {
        float a = sum[v], b = sq[v];
#pragma unroll
        for (int off = 32; off >= 1; off >>= 1) {
            a += __shfl_down(a, off, 64);
            b += __shfl_down(b, off, 64);
        }
        if (lane == 0) { red[wid][v] = a; red[wid][32 + v] = b; }
    }
    __syncthreads();
    if (threadIdx.x < 64) {
        float r = red[0][threadIdx.x] + red[1][threadIdx.x] +
                  red[2][threadIdx.x] + red[3][threadIdx.x];
        partials[blockIdx.x * 64 + threadIdx.x] = r;
    }
}

// ---------------------------------------------------------------------------
// Finalize 2: reduce -> BN2 scale/shift, fold BN2 + mean(1/3) into fc1.
// fw1s[j*32+c] = fw1[j*32+c] * scale2[c] / 3
// c1[j] = fb1[j] + sum_c fw1[j*32+c] * shift2[c]
// ---------------------------------------------------------------------------
__global__ __launch_bounds__(256) void k_fin2(const float* __restrict__ partials,
                                              const float* __restrict__ g2,
                                              const float* __restrict__ bt2,
                                              const float* __restrict__ fw1,
                                              const float* __restrict__ fb1,
                                              float* __restrict__ fw1s,
                                              float* __restrict__ c1,
                                              float Ninv, int nb)
{
    __shared__ float red[4][64];
    __shared__ float tot[64];
    __shared__ float ssc[32], ssh[32];
    int t = threadIdx.x;
    {
        int v = t & 63, c = t >> 6;
        float a = 0.f;
        for (int b = c; b < nb; b += 4) a += partials[b * 64 + v];
        red[c][v] = a;
    }
    __syncthreads();
    if (t < 64) {
        tot[t] = red[0][t] + red[1][t] + red[2][t] + red[3][t];
    }
    __syncthreads();
    if (t < 32) {
        float mean = tot[t] * Ninv;
        float var  = fmaxf(tot[32 + t] * Ninv - mean * mean, 0.f);
        float rstd = rsqrtf(var + EPSV);
        float sc = g2[t] * rstd;
        ssc[t] = sc;
        ssh[t] = bt2[t] - mean * sc;
    }
    __syncthreads();
    for (int idx = t; idx < 512; idx += 256) {
        int c = idx & 31;
        fw1s[idx] = fw1[idx] * ssc[c] * (1.0f / 3.0f);
    }
    if (t < 16) {
        float a = fb1[t];
#pragma unroll
        for (int c = 0; c < 32; ++c) a = fmaf(fw1[t * 32 + c], ssh[c], a);
        c1[t] = a;
    }
}

// ---------------------------------------------------------------------------
// Pass 3: full forward per sample -> out[i]
// ---------------------------------------------------------------------------
__global__ __launch_bounds__(256) void k_final(const float* __restrict__ x,
                                               const float* __restrict__ w1,
                                               const float* __restrict__ b1,
                                               const float* __restrict__ w2f,
                                               const float* __restrict__ b2f,
                                               const float* __restrict__ fw1s,
                                               const float* __restrict__ c1,
                                               const float* __restrict__ fw2,
                                               const float* __restrict__ fb2,
                                               float* __restrict__ out,
                                               int B)
{
    int i = blockIdx.x * 256 + threadIdx.x;
    if (i >= B) return;
    float x0 = x[3*i], x1 = x[3*i+1], x2 = x[3*i+2];

    float s[32];
#pragma unroll
    for (int g = 0; g < 16; ++g) {
        float wa = w1[3*g], wb = w1[3*g+1], wc = w1[3*g+2], bb = b1[g];
        float r0 = fmaxf(fmaf(wb, x0, fmaf(wc, x1, bb)), 0.f);
        float r1 = fmaxf(fmaf(wa, x0, fmaf(wb, x1, fmaf(wc, x2, bb))), 0.f);
        float r2 = fmaxf(fmaf(wa, x1, fmaf(wb, x2, bb)), 0.f);
#pragma unroll
        for (int j = 0; j < 2; ++j) {
            int o = 2 * g + j;
            float ua = w2f[3*o], ub = w2f[3*o+1], uc = w2f[3*o+2];
            float v0 = fmaxf(fmaf(ub, r0, fmaf(uc, r1, b2f[3*o+0])), 0.f);
            float v1 = fmaxf(fmaf(ua, r0, fmaf(ub, r1, fmaf(uc, r2, b2f[3*o+1]))), 0.f);
            float v2 = fmaxf(fmaf(ua, r1, fmaf(ub, r2, b2f[3*o+2])), 0.f);
            s[o] = v0 + v1 + v2;
        }
    }

    float acc[16];
#pragma unroll
    for (int j = 0; j < 16; ++j) acc[j] = c1[j];
#pragma unroll
    for (int c = 0; c < 32; ++c) {
        float sv = s[c];
#pragma unroll
        for (int j = 0; j < 16; ++j) acc[j] = fmaf(fw1s[j * 32 + c], sv, acc[j]);
    }
    float r = fb2[0];
#pragma unroll
    for (int j = 0; j < 16; ++j) r = fmaf(fw2[j], fmaxf(acc[j], 0.f), r);
    out[i] = r;
}

// ---------------------------------------------------------------------------
extern "C" void kernel_launch(void* const* d_in, const int* in_sizes, int n_in,
                              void* d_out, int out_size, void* d_ws, size_t ws_size,
                              hipStream_t stream)
{
    const float* x   = (const float*)d_in[0];
    const float* w1  = (const float*)d_in[1];
    const float* b1  = (const float*)d_in[2];
    const float* g1  = (const float*)d_in[3];
    const float* bt1 = (const float*)d_in[4];
    const float* w2  = (const float*)d_in[5];
    const float* b2  = (const float*)d_in[6];
    const float* g2  = (const float*)d_in[7];
    const float* bt2 = (const float*)d_in[8];
    const float* fw1 = (const float*)d_in[9];
    const float* fb1 = (const float*)d_in[10];
    const float* fw2 = (const float*)d_in[11];
    const float* fb2 = (const float*)d_in[12];

    int B = in_sizes[0] / 3;

    // pick stats grid so ws fits: need (nb*96 + 736) floats
    int nb = NB_STATS;
    while ((size_t)(nb * 96 + 736) * sizeof(float) > ws_size && nb > 1) nb >>= 1;

    float* ws   = (float*)d_ws;
    float* p1   = ws;                   // nb*32
    float* p2   = ws + (size_t)nb * 32; // nb*64
    float* w2f  = ws + (size_t)nb * 96; // 96
    float* b2f  = w2f + 96;             // 96
    float* fw1s = b2f + 96;             // 512
    float* c1   = fw1s + 512;           // 16

    float Ninv = 1.0f / (3.0f * (float)B);

    k_stats1<<<nb, 256, 0, stream>>>(x, w1, b1, p1, B);
    k_fin1<<<1, 256, 0, stream>>>(p1, g1, bt1, w2, b2, w2f, b2f, Ninv, nb);
    k_stats2<<<nb, 256, 0, stream>>>(x, w1, b1, w2f, b2f, p2, B);
    k_fin2<<<1, 256, 0, stream>>>(p2, g2, bt2, fw1, fb1, fw1s, c1, Ninv, nb);
    k_final<<<(B + 255) / 256, 256, 0, stream>>>(x, w1, b1, w2f, b2f, fw1s, c1,
                                                 fw2, fb2, (float*)d_out, B);
}

// Round 2
// 241.265 us; speedup vs baseline: 1.1886x; 1.1886x over previous
//
#include <hip/hip_runtime.h>
#include <math.h>

#define EPSV 1e-5f

// conv1 (3-tap, zero-pad) + relu at the 3 positions of one sample
__device__ __forceinline__ void conv3_relu(float x0, float x1, float x2,
                                           float wa, float wb, float wc, float bb,
                                           float& t0, float& t1, float& t2)
{
    t0 = fmaxf(fmaf(wb, x0, fmaf(wc, x1, bb)), 0.f);
    t1 = fmaxf(fmaf(wa, x0, fmaf(wb, x1, fmaf(wc, x2, bb))), 0.f);
    t2 = fmaxf(fmaf(wa, x1, fmaf(wb, x2, bb)), 0.f);
}

// ---------------------------------------------------------------------------
// Pass 1: per-channel sum/sumsq of relu(conv1(x)+b1). Weights lane-uniform
// (compiler keeps in SGPRs). 4 samples per iteration via float4 loads.
// partials[block*32 + v]: v<16 sum[ch v], v>=16 sq[ch v-16]
// ---------------------------------------------------------------------------
__global__ __launch_bounds__(256) void k_stats1(const float* __restrict__ x,
                                                const float* __restrict__ w1,
                                                const float* __restrict__ b1,
                                                float* __restrict__ partials,
                                                int B)
{
    float W[16][3], Bv[16];
#pragma unroll
    for (int o = 0; o < 16; ++o) {
        W[o][0] = w1[3*o]; W[o][1] = w1[3*o+1]; W[o][2] = w1[3*o+2];
        Bv[o] = b1[o];
    }
    float sum[16], sq[16];
#pragma unroll
    for (int i = 0; i < 16; ++i) { sum[i] = 0.f; sq[i] = 0.f; }

    auto acc1 = [&](float x0, float x1, float x2) {
#pragma unroll
        for (int o = 0; o < 16; ++o) {
            float t0, t1, t2;
            conv3_relu(x0, x1, x2, W[o][0], W[o][1], W[o][2], Bv[o], t0, t1, t2);
            sum[o] += t0 + t1 + t2;
            sq[o] = fmaf(t0, t0, fmaf(t1, t1, fmaf(t2, t2, sq[o])));
        }
    };

    long long t = (long long)blockIdx.x * 256 + threadIdx.x;
    long long nth = (long long)gridDim.x * 256;
    long long nquad = ((long long)B + 3) >> 2;
    for (long long qd = t; qd < nquad; qd += nth) {
        long long s0 = qd << 2;
        if (s0 + 4 <= (long long)B) {
            const float4* xp = (const float4*)(x + s0 * 3);
            float4 A = xp[0], Bq = xp[1], Cq = xp[2];
            acc1(A.x, A.y, A.z);
            acc1(A.w, Bq.x, Bq.y);
            acc1(Bq.z, Bq.w, Cq.x);
            acc1(Cq.y, Cq.z, Cq.w);
        } else {
            for (int k = 0; k < 4; ++k)
                if (s0 + k < (long long)B)
                    acc1(x[3*(s0+k)], x[3*(s0+k)+1], x[3*(s0+k)+2]);
        }
    }

    __shared__ float red[4][32];
    int lane = threadIdx.x & 63, wid = threadIdx.x >> 6;
#pragma unroll
    for (int v = 0; v < 16; ++v) {
        float a = sum[v], b = sq[v];
#pragma unroll
        for (int off = 32; off >= 1; off >>= 1) {
            a += __shfl_down(a, off, 64);
            b += __shfl_down(b, off, 64);
        }
        if (lane == 0) { red[wid][v] = a; red[wid][16 + v] = b; }
    }
    __syncthreads();
    if (threadIdx.x < 32) {
        partials[blockIdx.x * 32 + threadIdx.x] =
            red[0][threadIdx.x] + red[1][threadIdx.x] +
            red[2][threadIdx.x] + red[3][threadIdx.x];
    }
}

// ---------------------------------------------------------------------------
// Finalize 1: BN1 scale/shift, fold into conv2 weights (padding-aware bias).
// ---------------------------------------------------------------------------
__global__ __launch_bounds__(256) void k_fin1(const float* __restrict__ partials,
                                              const float* __restrict__ g1,
                                              const float* __restrict__ bt1,
                                              const float* __restrict__ w2,
                                              const float* __restrict__ b2,
                                              float* __restrict__ w2f,
                                              float* __restrict__ b2f,
                                              float Ninv, int nb)
{
    __shared__ float red[8][32];
    __shared__ float tot[32];
    __shared__ float ssc[16], ssh[16];
    int t = threadIdx.x;
    {
        int v = t & 31, c = t >> 5;
        float a = 0.f;
        for (int b = c; b < nb; b += 8) a += partials[b * 32 + v];
        red[c][v] = a;
    }
    __syncthreads();
    if (t < 32) {
        float a = 0.f;
#pragma unroll
        for (int c = 0; c < 8; ++c) a += red[c][t];
        tot[t] = a;
    }
    __syncthreads();
    if (t < 16) {
        float mean = tot[t] * Ninv;
        float var  = fmaxf(tot[16 + t] * Ninv - mean * mean, 0.f);
        float rstd = rsqrtf(var + EPSV);
        float sc = g1[t] * rstd;
        ssc[t] = sc;
        ssh[t] = bt1[t] - mean * sc;
    }
    __syncthreads();
    if (t < 96) {
        int o = t / 3, p = t % 3;
        int g = o >> 1;
        w2f[t] = w2[t] * ssc[g];
        float wv0 = w2[3*o], wv1 = w2[3*o+1], wv2 = w2[3*o+2];
        float sv = (p == 0) ? (wv1 + wv2) : ((p == 1) ? (wv0 + wv1 + wv2) : (wv0 + wv1));
        b2f[t] = b2[o] + ssh[g] * sv;
    }
}

// ---------------------------------------------------------------------------
// Pass 2: per-channel sum/sumsq of relu(conv2(bn1(relu1))), 32 channels.
// Lane-quad channel split: q=tid&3 handles conv groups [4q,4q+4) -> channels
// [8q,8q+8). Weights register-resident (64 floats/lane). 2 samples/iter.
// partials[block*64 + v]: v<32 sum[ch v], v>=32 sq[ch v-32]
// ---------------------------------------------------------------------------
__global__ __launch_bounds__(256) void k_stats2(const float* __restrict__ x,
                                                const float* __restrict__ w1,
                                                const float* __restrict__ b1,
                                                const float* __restrict__ w2f,
                                                const float* __restrict__ b2f,
                                                float* __restrict__ partials,
                                                int B)
{
    const int q = threadIdx.x & 3;
    const int g0 = 4 * q;
    float W[4][3], Bv[4], U[8][3], C[8][3];
#pragma unroll
    for (int g = 0; g < 4; ++g) {
        W[g][0] = w1[3*(g0+g)]; W[g][1] = w1[3*(g0+g)+1]; W[g][2] = w1[3*(g0+g)+2];
        Bv[g] = b1[g0+g];
    }
#pragma unroll
    for (int j = 0; j < 8; ++j) {
        int o = 8*q + j;
        U[j][0] = w2f[3*o]; U[j][1] = w2f[3*o+1]; U[j][2] = w2f[3*o+2];
        C[j][0] = b2f[3*o]; C[j][1] = b2f[3*o+1]; C[j][2] = b2f[3*o+2];
    }
    float sum[8], sq[8];
#pragma unroll
    for (int i = 0; i < 8; ++i) { sum[i] = 0.f; sq[i] = 0.f; }

    auto acc2 = [&](float x0, float x1, float x2) {
#pragma unroll
        for (int g = 0; g < 4; ++g) {
            float r0, r1, r2;
            conv3_relu(x0, x1, x2, W[g][0], W[g][1], W[g][2], Bv[g], r0, r1, r2);
#pragma unroll
            for (int jj = 0; jj < 2; ++jj) {
                int j = 2*g + jj;
                float v0 = fmaxf(fmaf(U[j][1], r0, fmaf(U[j][2], r1, C[j][0])), 0.f);
                float v1 = fmaxf(fmaf(U[j][0], r0, fmaf(U[j][1], r1, fmaf(U[j][2], r2, C[j][1]))), 0.f);
                float v2 = fmaxf(fmaf(U[j][0], r1, fmaf(U[j][1], r2, C[j][2])), 0.f);
                sum[j] += v0 + v1 + v2;
                sq[j] = fmaf(v0, v0, fmaf(v1, v1, fmaf(v2, v2, sq[j])));
            }
        }
    };

    long long tq = ((long long)blockIdx.x * 256 + threadIdx.x) >> 2;
    long long nthq = ((long long)gridDim.x * 256) >> 2;
    long long npair = ((long long)B + 1) >> 1;
    for (long long sp = tq; sp < npair; sp += nthq) {
        long long s0 = sp << 1;
        if (s0 + 2 <= (long long)B) {
            const float2* xp = (const float2*)(x + sp * 6);
            float2 a = xp[0], b = xp[1], c = xp[2];
            acc2(a.x, a.y, b.x);
            acc2(b.y, c.x, c.y);
        } else if (s0 < (long long)B) {
            acc2(x[3*s0], x[3*s0+1], x[3*s0+2]);
        }
    }

    __shared__ float red[4][64];
    int lane = threadIdx.x & 63, wid = threadIdx.x >> 6;
#pragma unroll
    for (int v = 0; v < 8; ++v) {
        float a = sum[v], b = sq[v];
#pragma unroll
        for (int off = 4; off <= 32; off <<= 1) {
            a += __shfl_down(a, off, 64);
            b += __shfl_down(b, off, 64);
        }
        if (lane < 4) { red[wid][8*lane + v] = a; red[wid][32 + 8*lane + v] = b; }
    }
    __syncthreads();
    if (threadIdx.x < 64) {
        partials[blockIdx.x * 64 + threadIdx.x] =
            red[0][threadIdx.x] + red[1][threadIdx.x] +
            red[2][threadIdx.x] + red[3][threadIdx.x];
    }
}

// ---------------------------------------------------------------------------
// Finalize 2: BN2 scale/shift, fold BN2 + mean(1/3) into fc1.
// ---------------------------------------------------------------------------
__global__ __launch_bounds__(256) void k_fin2(const float* __restrict__ partials,
                                              const float* __restrict__ g2,
                                              const float* __restrict__ bt2,
                                              const float* __restrict__ fw1,
                                              const float* __restrict__ fb1,
                                              float* __restrict__ fw1s,
                                              float* __restrict__ c1,
                                              float Ninv, int nb)
{
    __shared__ float red[4][64];
    __shared__ float tot[64];
    __shared__ float ssc[32], ssh[32];
    int t = threadIdx.x;
    {
        int v = t & 63, c = t >> 6;
        float a = 0.f;
        for (int b = c; b < nb; b += 4) a += partials[b * 64 + v];
        red[c][v] = a;
    }
    __syncthreads();
    if (t < 64) tot[t] = red[0][t] + red[1][t] + red[2][t] + red[3][t];
    __syncthreads();
    if (t < 32) {
        float mean = tot[t] * Ninv;
        float var  = fmaxf(tot[32 + t] * Ninv - mean * mean, 0.f);
        float rstd = rsqrtf(var + EPSV);
        float sc = g2[t] * rstd;
        ssc[t] = sc;
        ssh[t] = bt2[t] - mean * sc;
    }
    __syncthreads();
    for (int idx = t; idx < 512; idx += 256) {
        int c = idx & 31;
        fw1s[idx] = fw1[idx] * ssc[c] * (1.0f / 3.0f);
    }
    if (t < 16) {
        float a = fb1[t];
#pragma unroll
        for (int c = 0; c < 32; ++c) a = fmaf(fw1[t * 32 + c], ssh[c], a);
        c1[t] = a;
    }
}

// ---------------------------------------------------------------------------
// Pass 3: full forward. Lane-quad split: q=tid&3 handles conv groups
// [4q,4q+4) (channels [8q,8q+8)) + its 8-column slice of fc1 (128 regs).
// fc1 done j-outer (1 live acc), quad-reduced via shfl, fc2 on q==0 lanes.
// ---------------------------------------------------------------------------
__global__ __launch_bounds__(256) void k_final(const float* __restrict__ x,
                                               const float* __restrict__ w1,
                                               const float* __restrict__ b1,
                                               const float* __restrict__ w2f,
                                               const float* __restrict__ b2f,
                                               const float* __restrict__ fw1s,
                                               const float* __restrict__ c1,
                                               const float* __restrict__ fw2,
                                               const float* __restrict__ fb2,
                                               float* __restrict__ out,
                                               int B)
{
    const int q = threadIdx.x & 3;
    const int g0 = 4 * q;
    float W[4][3], Bv[4], U[8][3], C[8][3], F[8][16];
#pragma unroll
    for (int g = 0; g < 4; ++g) {
        W[g][0] = w1[3*(g0+g)]; W[g][1] = w1[3*(g0+g)+1]; W[g][2] = w1[3*(g0+g)+2];
        Bv[g] = b1[g0+g];
    }
#pragma unroll
    for (int j = 0; j < 8; ++j) {
        int o = 8*q + j;
        U[j][0] = w2f[3*o]; U[j][1] = w2f[3*o+1]; U[j][2] = w2f[3*o+2];
        C[j][0] = b2f[3*o]; C[j][1] = b2f[3*o+1]; C[j][2] = b2f[3*o+2];
    }
#pragma unroll
    for (int cc = 0; cc < 8; ++cc)
#pragma unroll
        for (int j = 0; j < 16; ++j)
            F[cc][j] = fw1s[j * 32 + 8*q + cc];

    // lane-uniform -> SGPRs
    float c1v[16], w2v[16];
#pragma unroll
    for (int j = 0; j < 16; ++j) { c1v[j] = c1[j]; w2v[j] = fw2[j]; }
    float fb2v = fb2[0];

    long long tq = ((long long)blockIdx.x * 256 + threadIdx.x) >> 2;
    long long nthq = ((long long)gridDim.x * 256) >> 2;
    for (long long s = tq; s < (long long)B; s += nthq) {
        float x0 = x[3*s], x1 = x[3*s+1], x2 = x[3*s+2];

        float s8[8];
#pragma unroll
        for (int g = 0; g < 4; ++g) {
            float r0, r1, r2;
            conv3_relu(x0, x1, x2, W[g][0], W[g][1], W[g][2], Bv[g], r0, r1, r2);
#pragma unroll
            for (int jj = 0; jj < 2; ++jj) {
                int j = 2*g + jj;
                float v0 = fmaxf(fmaf(U[j][1], r0, fmaf(U[j][2], r1, C[j][0])), 0.f);
                float v1 = fmaxf(fmaf(U[j][0], r0, fmaf(U[j][1], r1, fmaf(U[j][2], r2, C[j][1]))), 0.f);
                float v2 = fmaxf(fmaf(U[j][0], r1, fmaf(U[j][1], r2, C[j][2])), 0.f);
                s8[j] = v0 + v1 + v2;
            }
        }

        float outv = fb2v;
#pragma unroll
        for (int j = 0; j < 16; ++j) {
            float a = 0.f;
#pragma unroll
            for (int cc = 0; cc < 8; ++cc) a = fmaf(F[cc][j], s8[cc], a);
            a += __shfl_down(a, 1, 64);
            a += __shfl_down(a, 2, 64);
            outv = fmaf(w2v[j], fmaxf(a + c1v[j], 0.f), outv);
        }
        if (q == 0) out[s] = outv;
    }
}

// ---------------------------------------------------------------------------
extern "C" void kernel_launch(void* const* d_in, const int* in_sizes, int n_in,
                              void* d_out, int out_size, void* d_ws, size_t ws_size,
                              hipStream_t stream)
{
    const float* x   = (const float*)d_in[0];
    const float* w1  = (const float*)d_in[1];
    const float* b1  = (const float*)d_in[2];
    const float* g1  = (const float*)d_in[3];
    const float* bt1 = (const float*)d_in[4];
    const float* w2  = (const float*)d_in[5];
    const float* b2  = (const float*)d_in[6];
    const float* g2  = (const float*)d_in[7];
    const float* bt2 = (const float*)d_in[8];
    const float* fw1 = (const float*)d_in[9];
    const float* fb1 = (const float*)d_in[10];
    const float* fw2 = (const float*)d_in[11];
    const float* fb2 = (const float*)d_in[12];

    int B = in_sizes[0] / 3;

    int nb1 = 768, nb2 = 768;
    while ((size_t)(nb1 * 32 + nb2 * 64 + 736) * sizeof(float) > ws_size &&
           nb1 > 1) { nb1 >>= 1; nb2 >>= 1; }

    float* ws   = (float*)d_ws;
    float* p1   = ws;                               // nb1*32
    float* p2   = ws + (size_t)nb1 * 32;            // nb2*64
    float* w2f  = p2 + (size_t)nb2 * 64;            // 96
    float* b2f  = w2f + 96;                         // 96
    float* fw1s = b2f + 96;                         // 512
    float* c1   = fw1s + 512;                       // 16

    float Ninv = 1.0f / (3.0f * (float)B);

    k_stats1<<<nb1, 256, 0, stream>>>(x, w1, b1, p1, B);
    k_fin1<<<1, 256, 0, stream>>>(p1, g1, bt1, w2, b2, w2f, b2f, Ninv, nb1);
    k_stats2<<<nb2, 256, 0, stream>>>(x, w1, b1, w2f, b2f, p2, B);
    k_fin2<<<1, 256, 0, stream>>>(p2, g2, bt2, fw1, fb1, fw1s, c1, Ninv, nb2);
    k_final<<<1536, 256, 0, stream>>>(x, w1, b1, w2f, b2f, fw1s, c1,
                                      fw2, fb2, (float*)d_out, B);
}